// Round 1
// baseline (175.217 us; speedup 1.0000x reference)
//
#include <hip/hip_runtime.h>

// WaveCell FDTD step, fp32, B=8, NY=NX=1024.
// y = inv*(8*h1 - (4-2b)*h2 + c^2*lap),  b = bg + rho/(1+h1^2),
// c = c_linear + 0.01*rho*h1^2, inv = 1/(4+2b), lap = 5pt zero-pad stencil.
// Outputs concatenated: [y (8M floats), h1 copy (8M floats)].

#define NYDIM 1024
#define NXDIM 1024
#define NX4   (NXDIM / 4)   // 256 float4 per row

__device__ __forceinline__ float wave_pt(float h1x, float h2x, float clx,
                                         float rx, float bgx, float lap) {
    float s   = h1x * h1x;
    float b   = bgx + rx / (1.0f + s);
    float c   = clx + 0.01f * rx * s;
    float inv = 1.0f / (4.0f + 2.0f * b);
    return inv * (8.0f * h1x - (4.0f - 2.0f * b) * h2x + c * c * lap);
}

__global__ __launch_bounds__(256) void wavecell_kernel(
    const float* __restrict__ h1,
    const float* __restrict__ h2,
    const float* __restrict__ cl,
    const float* __restrict__ rho,
    const float* __restrict__ bg,
    float* __restrict__ out,
    int n4)   // number of float4 elements = B*NY*NX/4
{
    int gid = blockIdx.x * blockDim.x + threadIdx.x;
    if (gid >= n4) return;

    int x4  = gid & (NX4 - 1);       // float4-column in row
    int row = gid >> 8;              // global row index (b*NY + y)
    int y   = row & (NYDIM - 1);     // row within image

    const float4* h1v = (const float4*)h1;

    float4 hc  = h1v[gid];
    float4 top = make_float4(0.f, 0.f, 0.f, 0.f);
    float4 bot = make_float4(0.f, 0.f, 0.f, 0.f);
    if (y > 0)         top = h1v[gid - NX4];
    if (y < NYDIM - 1) bot = h1v[gid + NX4];
    float left  = (x4 > 0)       ? h1[gid * 4 - 1] : 0.0f;
    float right = (x4 < NX4 - 1) ? h1[gid * 4 + 4] : 0.0f;

    float4 h2c = ((const float4*)h2)[gid];
    float4 clc = ((const float4*)cl)[gid];
    float4 rc  = ((const float4*)rho)[gid];
    float4 bgc = ((const float4*)bg)[y * NX4 + x4];

    // 5-point Laplacian, h=1, zero padding
    float lapx = top.x + bot.x + left  + hc.y - 4.0f * hc.x;
    float lapy = top.y + bot.y + hc.x  + hc.z - 4.0f * hc.y;
    float lapz = top.z + bot.z + hc.y  + hc.w - 4.0f * hc.z;
    float lapw = top.w + bot.w + hc.z  + right - 4.0f * hc.w;

    float4 yv;
    yv.x = wave_pt(hc.x, h2c.x, clc.x, rc.x, bgc.x, lapx);
    yv.y = wave_pt(hc.y, h2c.y, clc.y, rc.y, bgc.y, lapy);
    yv.z = wave_pt(hc.z, h2c.z, clc.z, rc.z, bgc.z, lapz);
    yv.w = wave_pt(hc.w, h2c.w, clc.w, rc.w, bgc.w, lapw);

    float4* outv = (float4*)out;
    outv[gid]      = yv;   // output 0: y
    outv[n4 + gid] = hc;   // output 1: h1 passthrough
}

extern "C" void kernel_launch(void* const* d_in, const int* in_sizes, int n_in,
                              void* d_out, int out_size, void* d_ws, size_t ws_size,
                              hipStream_t stream) {
    const float* h1  = (const float*)d_in[0];
    const float* h2  = (const float*)d_in[1];
    const float* cl  = (const float*)d_in[2];
    const float* rho = (const float*)d_in[3];
    const float* bg  = (const float*)d_in[4];
    float* out = (float*)d_out;

    int n  = in_sizes[0];      // 8*1024*1024
    int n4 = n / 4;            // 2097152 float4s
    int threads = 256;
    int blocks  = (n4 + threads - 1) / threads;  // 8192
    wavecell_kernel<<<blocks, threads, 0, stream>>>(h1, h2, cl, rho, bg, out, n4);
}